// Round 1
// baseline (998.692 us; speedup 1.0000x reference)
//
#include <hip/hip_runtime.h>
#include <math.h>

#define NPIX 262144   // 512*512

__device__ __forceinline__ int brev9(int i) { return (int)(__brev((unsigned)i) >> 23); }

__device__ __forceinline__ void init_tw(float* twr, float* twi, int t) {
  // forward twiddles: exp(-i*pi*k/256), k=0..255
  for (int e = t; e < 256; e += 256) {
    float ang = -3.14159265358979323846f * (float)e / 256.0f;
    float s, c;
    sincosf(ang, &s, &c);
    twr[e] = c; twi[e] = s;
  }
}

// 512-point radix-2 DIT FFT on LDS. 256 threads, data must be loaded
// bit-reversed (lds[brev9(i)] = x[i]); caller syncs after load.
template<bool FWD>
__device__ __forceinline__ void fft512(float* sr, float* si,
                                       const float* twr, const float* twi, int t) {
  #pragma unroll
  for (int s = 0; s < 9; s++) {
    int half = 1 << s;
    int j = t & (half - 1);
    int k = ((t >> s) << (s + 1)) | j;
    int tk = j << (8 - s);
    float wr = twr[tk];
    float wi = FWD ? twi[tk] : -twi[tk];
    float vr = sr[k + half], vi = si[k + half];
    float tr = vr * wr - vi * wi;
    float ti = vr * wi + vi * wr;
    float ur = sr[k], ui = si[k];
    sr[k] = ur + tr;        si[k] = ui + ti;
    sr[k + half] = ur - tr; si[k + half] = ui - ti;
    __syncthreads();
  }
}

__global__ __launch_bounds__(256) void k_fft_row_fwd(const float* __restrict__ x,
                                                     float2* __restrict__ xf) {
  __shared__ float sr[512], si[512], twr[256], twi[256];
  int t = threadIdx.x;
  int row = blockIdx.x & 511;
  int img = blockIdx.x >> 9;
  const float* p = x + (size_t)img * NPIX + (size_t)row * 512;
  init_tw(twr, twi, t);
  for (int i = t; i < 512; i += 256) { int r = brev9(i); sr[r] = p[i]; si[r] = 0.0f; }
  __syncthreads();
  fft512<true>(sr, si, twr, twi, t);
  float2* q = xf + (size_t)img * NPIX + (size_t)row * 512;
  for (int i = t; i < 512; i += 256) q[i] = make_float2(sr[i], si[i]);
}

__global__ __launch_bounds__(256) void k_fft_col_fwd(float2* __restrict__ xf) {
  __shared__ float sr[512], si[512], twr[256], twi[256];
  int t = threadIdx.x;
  int col = blockIdx.x & 511;
  int img = blockIdx.x >> 9;
  float2* p = xf + (size_t)img * NPIX + col;
  init_tw(twr, twi, t);
  for (int i = t; i < 512; i += 256) {
    int r = brev9(i);
    float2 v = p[(size_t)i * 512];
    sr[r] = v.x; si[r] = v.y;
  }
  __syncthreads();
  fft512<true>(sr, si, twr, twi, t);
  for (int i = t; i < 512; i += 256) p[(size_t)i * 512] = make_float2(sr[i], si[i]);
}

// x_mag with the all-axes fftshift quirk:
// xmag[b][c][h][w] = log10(|xf[(b+4)%8][(c+2)%3][(h+256)%512][(w+256)%512]| + 1)
__global__ __launch_bounds__(256) void k_xmag(const float2* __restrict__ xf,
                                              float* __restrict__ xmag) {
  int idx = blockIdx.x * 256 + threadIdx.x;   // 0 .. 6291455
  int w = idx & 511;
  int h = (idx >> 9) & 511;
  int bc = idx >> 18;            // 0..23
  int b = bc / 3, c = bc - 3 * b;
  int simg = ((b + 4) & 7) * 3 + ((c + 2) % 3);
  float2 v = xf[(size_t)simg * NPIX + (size_t)((h + 256) & 511) * 512 + ((w + 256) & 511)];
  xmag[idx] = log10f(sqrtf(v.x * v.x + v.y * v.y) + 1.0f);
}

// conv1(6->16, 3x3, pad1) + bias + relu + 2x2 avgpool, fused.
// Thread: one pooled pixel for 4 output channels.
__global__ __launch_bounds__(256) void k_conv1(const float* __restrict__ x,
                                               const float* __restrict__ xmag,
                                               const float* __restrict__ w1,
                                               const float* __restrict__ b1,
                                               float* __restrict__ out) {
  int pw = threadIdx.x;          // 0..255
  int ph = blockIdx.x;           // 0..255
  int z  = blockIdx.y;           // 0..31 : b*4 + ocGroup
  int b  = z >> 2;
  int og = (z & 3) << 2;
  float acc[4][4];
  #pragma unroll
  for (int o = 0; o < 4; o++)
    #pragma unroll
    for (int q = 0; q < 4; q++) acc[o][q] = 0.0f;
  int h0 = 2 * ph - 1, w0 = 2 * pw - 1;
  for (int ic = 0; ic < 6; ic++) {
    const float* src = (ic < 3) ? (x + (size_t)(b * 3 + ic) * NPIX)
                                : (xmag + (size_t)(b * 3 + ic - 3) * NPIX);
    float patch[4][4];
    #pragma unroll
    for (int dy = 0; dy < 4; dy++) {
      int yy = h0 + dy;
      #pragma unroll
      for (int dx = 0; dx < 4; dx++) {
        int xx = w0 + dx;
        patch[dy][dx] = ((unsigned)yy < 512u && (unsigned)xx < 512u) ? src[yy * 512 + xx] : 0.0f;
      }
    }
    #pragma unroll
    for (int o = 0; o < 4; o++) {
      const float* wk = w1 + (size_t)((og + o) * 6 + ic) * 9;
      float k0 = wk[0], k1 = wk[1], k2 = wk[2], k3 = wk[3], k4 = wk[4],
            k5 = wk[5], k6 = wk[6], k7 = wk[7], k8 = wk[8];
      #pragma unroll
      for (int r = 0; r < 2; r++)
        #pragma unroll
        for (int cc = 0; cc < 2; cc++) {
          float s = k0 * patch[r][cc]     + k1 * patch[r][cc + 1]     + k2 * patch[r][cc + 2]
                  + k3 * patch[r + 1][cc] + k4 * patch[r + 1][cc + 1] + k5 * patch[r + 1][cc + 2]
                  + k6 * patch[r + 2][cc] + k7 * patch[r + 2][cc + 1] + k8 * patch[r + 2][cc + 2];
          acc[o][r * 2 + cc] += s;
        }
    }
  }
  #pragma unroll
  for (int o = 0; o < 4; o++) {
    float bias = b1[og + o];
    float v = fmaxf(acc[o][0] + bias, 0.0f) + fmaxf(acc[o][1] + bias, 0.0f)
            + fmaxf(acc[o][2] + bias, 0.0f) + fmaxf(acc[o][3] + bias, 0.0f);
    out[((size_t)(b * 16 + og + o) * 256 + ph) * 256 + pw] = v * 0.25f;
  }
}

// conv2(16->32) + bias + relu + pool, fused. Thread: one pooled pixel x 4 oc.
__global__ __launch_bounds__(128) void k_conv2(const float* __restrict__ in,
                                               const float* __restrict__ w2,
                                               const float* __restrict__ b2,
                                               float* __restrict__ out) {
  int pw = threadIdx.x;          // 0..127
  int ph = blockIdx.x;           // 0..127
  int z  = blockIdx.y;           // 0..63 : b*8 + ocGroup
  int b  = z >> 3;
  int og = (z & 7) << 2;
  float acc[4][4];
  #pragma unroll
  for (int o = 0; o < 4; o++)
    #pragma unroll
    for (int q = 0; q < 4; q++) acc[o][q] = 0.0f;
  int h0 = 2 * ph - 1, w0 = 2 * pw - 1;
  for (int ic = 0; ic < 16; ic++) {
    const float* src = in + (size_t)(b * 16 + ic) * 65536;
    float patch[4][4];
    #pragma unroll
    for (int dy = 0; dy < 4; dy++) {
      int yy = h0 + dy;
      #pragma unroll
      for (int dx = 0; dx < 4; dx++) {
        int xx = w0 + dx;
        patch[dy][dx] = ((unsigned)yy < 256u && (unsigned)xx < 256u) ? src[yy * 256 + xx] : 0.0f;
      }
    }
    #pragma unroll
    for (int o = 0; o < 4; o++) {
      const float* wk = w2 + (size_t)((og + o) * 16 + ic) * 9;
      float k0 = wk[0], k1 = wk[1], k2 = wk[2], k3 = wk[3], k4 = wk[4],
            k5 = wk[5], k6 = wk[6], k7 = wk[7], k8 = wk[8];
      #pragma unroll
      for (int r = 0; r < 2; r++)
        #pragma unroll
        for (int cc = 0; cc < 2; cc++) {
          float s = k0 * patch[r][cc]     + k1 * patch[r][cc + 1]     + k2 * patch[r][cc + 2]
                  + k3 * patch[r + 1][cc] + k4 * patch[r + 1][cc + 1] + k5 * patch[r + 1][cc + 2]
                  + k6 * patch[r + 2][cc] + k7 * patch[r + 2][cc + 1] + k8 * patch[r + 2][cc + 2];
          acc[o][r * 2 + cc] += s;
        }
    }
  }
  #pragma unroll
  for (int o = 0; o < 4; o++) {
    float bias = b2[og + o];
    float v = fmaxf(acc[o][0] + bias, 0.0f) + fmaxf(acc[o][1] + bias, 0.0f)
            + fmaxf(acc[o][2] + bias, 0.0f) + fmaxf(acc[o][3] + bias, 0.0f);
    out[((size_t)(b * 32 + og + o) * 128 + ph) * 128 + pw] = v * 0.25f;
  }
}

// conv3(32->64) + spatial mean (bias added later in FC). Thread: one pixel x 4 oc.
__global__ __launch_bounds__(128) void k_conv3(const float* __restrict__ in,
                                               const float* __restrict__ w3,
                                               float* __restrict__ ymean) {
  int w = threadIdx.x;           // 0..127
  int h = blockIdx.x;            // 0..127
  int z = blockIdx.y;            // 0..127 : b*16 + ocGroup
  int b  = z >> 4;
  int og = (z & 15) << 2;
  float acc[4] = {0.f, 0.f, 0.f, 0.f};
  for (int ic = 0; ic < 32; ic++) {
    const float* src = in + (size_t)(b * 32 + ic) * 16384;
    float patch[3][3];
    #pragma unroll
    for (int dy = 0; dy < 3; dy++) {
      int yy = h - 1 + dy;
      #pragma unroll
      for (int dx = 0; dx < 3; dx++) {
        int xx = w - 1 + dx;
        patch[dy][dx] = ((unsigned)yy < 128u && (unsigned)xx < 128u) ? src[yy * 128 + xx] : 0.0f;
      }
    }
    #pragma unroll
    for (int o = 0; o < 4; o++) {
      const float* wk = w3 + (size_t)((og + o) * 32 + ic) * 9;
      acc[o] += wk[0] * patch[0][0] + wk[1] * patch[0][1] + wk[2] * patch[0][2]
              + wk[3] * patch[1][0] + wk[4] * patch[1][1] + wk[5] * patch[1][2]
              + wk[6] * patch[2][0] + wk[7] * patch[2][1] + wk[8] * patch[2][2];
    }
  }
  #pragma unroll
  for (int o = 0; o < 4; o++) {
    float v = acc[o] * (1.0f / 16384.0f);
    #pragma unroll
    for (int off = 32; off > 0; off >>= 1) v += __shfl_down(v, off, 64);
    if ((threadIdx.x & 63) == 0) atomicAdd(&ymean[b * 64 + og + o], v);
  }
}

// FC1 -> FC2 -> leaky_relu(0.01). Single block.
__global__ __launch_bounds__(256) void k_fc(const float* __restrict__ ymean,
                                            const float* __restrict__ b3,
                                            const float* __restrict__ fw1,
                                            const float* __restrict__ fb1,
                                            const float* __restrict__ fw2,
                                            const float* __restrict__ fb2,
                                            float* __restrict__ vs_out) {
  __shared__ float y[512];     // 8x64 (conv3 mean + bias)
  __shared__ float h1[2048];   // 8x256
  int t = threadIdx.x;
  for (int e = t; e < 512; e += 256) y[e] = ymean[e] + b3[e & 63];
  __syncthreads();
  for (int e = t; e < 2048; e += 256) {
    int b = e >> 8, j = e & 255;
    float s = fb1[j];
    for (int k = 0; k < 64; k++) s += y[b * 64 + k] * fw1[j * 64 + k];
    h1[e] = s;
  }
  __syncthreads();
  for (int e = t; e < 800; e += 256) {
    int b = e / 100, i = e - 100 * b;
    float s = fb2[i];
    for (int j = 0; j < 256; j++) s += h1[b * 256 + j] * fw2[i * 256 + j];
    vs_out[e] = (s >= 0.0f) ? s : 0.01f * s;
  }
}

// fq_mask[b][h][w] = value_set[b][searchsorted(radius_set, dist(h,w), 'left').clip(0,99)]
__global__ __launch_bounds__(256) void k_mask(const float* __restrict__ vs,
                                              float* __restrict__ fq_mask) {
  int idx = blockIdx.x * 256 + threadIdx.x;   // 0 .. 262143
  int h = idx >> 9, w = idx & 511;
  float da = (float)h - 256.0f, db = (float)w - 256.0f;
  float dist = sqrtf(da * da + db * db);      // exact integer radicand in f32
  // searchsorted left: first i with radius_set[i] >= dist; radius computed exactly as ref
  int lo = 0, hi = 100;
  while (lo < hi) {
    int mid = (lo + hi) >> 1;
    float r = (362.03867196751236f * (float)(mid + 1)) * 0.01f;
    if (r < dist) lo = mid + 1; else hi = mid;
  }
  int bin = lo > 99 ? 99 : lo;
  #pragma unroll
  for (int b = 0; b < 8; b++)
    fq_mask[(size_t)b * NPIX + idx] = vs[b * 100 + bin];
}

// inverse FFT over rows, with spectrum modulation fused on load.
// low[b][c][u][v] = xf[b][c][u][v] * fq_mask[(b+4)%8][(u+256)%512][(v+256)%512]
__global__ __launch_bounds__(256) void k_ifft_row_mod(float2* __restrict__ xf,
                                                      const float* __restrict__ fq_mask) {
  __shared__ float sr[512], si[512], twr[256], twi[256];
  int t = threadIdx.x;
  int row = blockIdx.x & 511;
  int img = blockIdx.x >> 9;
  int b = img / 3;
  int bm = (b + 4) & 7;
  const float* mrow = fq_mask + (size_t)bm * NPIX + (size_t)((row + 256) & 511) * 512;
  float2* p = xf + (size_t)img * NPIX + (size_t)row * 512;
  init_tw(twr, twi, t);
  for (int i = t; i < 512; i += 256) {
    int r = brev9(i);
    float m = mrow[(i + 256) & 511];
    float2 v = p[i];
    sr[r] = v.x * m; si[r] = v.y * m;
  }
  __syncthreads();
  fft512<false>(sr, si, twr, twi, t);
  for (int i = t; i < 512; i += 256) p[i] = make_float2(sr[i], si[i]);
}

// inverse FFT over columns, scale 1/(512*512), clip real -> lowpass output.
__global__ __launch_bounds__(256) void k_ifft_col_out(float2* __restrict__ xf,
                                                      float* __restrict__ lowpass) {
  __shared__ float sr[512], si[512], twr[256], twi[256];
  int t = threadIdx.x;
  int col = blockIdx.x & 511;
  int img = blockIdx.x >> 9;
  float2* p = xf + (size_t)img * NPIX + col;
  init_tw(twr, twi, t);
  for (int i = t; i < 512; i += 256) {
    int r = brev9(i);
    float2 v = p[(size_t)i * 512];
    sr[r] = v.x; si[r] = v.y;
  }
  __syncthreads();
  fft512<false>(sr, si, twr, twi, t);
  const float sc = 1.0f / 262144.0f;
  for (int i = t; i < 512; i += 256) {
    float v = sr[i] * sc;
    v = fminf(fmaxf(v, 0.0f), 1.0f);
    lowpass[(size_t)img * NPIX + (size_t)i * 512 + col] = v;
  }
}

extern "C" void kernel_launch(void* const* d_in, const int* in_sizes, int n_in,
                              void* d_out, int out_size, void* d_ws, size_t ws_size,
                              hipStream_t stream) {
  const float* x   = (const float*)d_in[0];
  const float* w1  = (const float*)d_in[1];
  const float* b1  = (const float*)d_in[2];
  const float* w2  = (const float*)d_in[3];
  const float* b2  = (const float*)d_in[4];
  const float* w3  = (const float*)d_in[5];
  const float* b3  = (const float*)d_in[6];
  const float* fw1 = (const float*)d_in[7];
  const float* fb1 = (const float*)d_in[8];
  const float* fw2 = (const float*)d_in[9];
  const float* fb2 = (const float*)d_in[10];

  float* lowpass = (float*)d_out;            // 8*3*512*512 = 6291456
  float* fq_mask = lowpass + 6291456;        // 8*512*512   = 2097152
  float* vs      = fq_mask + 2097152;        // 8*100       = 800

  // workspace layout (floats): xf complex 24*512*512 | xmag (aliased by pooled2) | pooled1 | ymean
  float* base    = (float*)d_ws;
  float2* xf     = (float2*)base;            // 12582912 floats
  float* xmag    = base + 12582912;          // 6291456 floats
  float* pooled1 = xmag + 6291456;           // 8388608 floats
  float* pooled2 = xmag;                     // alias: xmag dead after conv1 (needs 4194304)
  float* ymean   = pooled1 + 8388608;        // 512 floats

  // forward 2D FFT (rows then cols), unshifted layout
  k_fft_row_fwd<<<dim3(24 * 512), 256, 0, stream>>>(x, xf);
  k_fft_col_fwd<<<dim3(24 * 512), 256, 0, stream>>>(xf);

  // log-magnitude (with all-axes fftshift permutation)
  k_xmag<<<6291456 / 256, 256, 0, stream>>>(xf, xmag);

  // conv stack
  k_conv1<<<dim3(256, 32), 256, 0, stream>>>(x, xmag, w1, b1, pooled1);
  k_conv2<<<dim3(128, 64), 128, 0, stream>>>(pooled1, w2, b2, pooled2);
  hipMemsetAsync(ymean, 0, 512 * sizeof(float), stream);
  k_conv3<<<dim3(128, 128), 128, 0, stream>>>(pooled2, w3, ymean);

  // FC head -> value_set (written straight to d_out region)
  k_fc<<<1, 256, 0, stream>>>(ymean, b3, fw1, fb1, fw2, fb2, vs);

  // radial mask
  k_mask<<<1024, 256, 0, stream>>>(vs, fq_mask);

  // modulate + inverse 2D FFT + clip
  k_ifft_row_mod<<<dim3(24 * 512), 256, 0, stream>>>(xf, fq_mask);
  k_ifft_col_out<<<dim3(24 * 512), 256, 0, stream>>>(xf, lowpass);
}

// Round 2
// 911.814 us; speedup vs baseline: 1.0953x; 1.0953x over previous
//
#include <hip/hip_runtime.h>
#include <math.h>

#define NPIX 262144   // 512*512

__device__ __forceinline__ int brev9(int i) { return (int)(__brev((unsigned)i) >> 23); }

__device__ __forceinline__ void init_tw(float* twr, float* twi, int t) {
  // forward twiddles: exp(-i*pi*k/256), k=0..255
  for (int e = t; e < 256; e += 256) {
    float ang = -3.14159265358979323846f * (float)e / 256.0f;
    float s, c;
    sincosf(ang, &s, &c);
    twr[e] = c; twi[e] = s;
  }
}

// 512-point radix-2 DIT FFT on LDS. 256 threads, data must be loaded
// bit-reversed (lds[brev9(i)] = x[i]); caller syncs after load.
template<bool FWD>
__device__ __forceinline__ void fft512(float* sr, float* si,
                                       const float* twr, const float* twi, int t) {
  #pragma unroll
  for (int s = 0; s < 9; s++) {
    int half = 1 << s;
    int j = t & (half - 1);
    int k = ((t >> s) << (s + 1)) | j;
    int tk = j << (8 - s);
    float wr = twr[tk];
    float wi = FWD ? twi[tk] : -twi[tk];
    float vr = sr[k + half], vi = si[k + half];
    float tr = vr * wr - vi * wi;
    float ti = vr * wi + vi * wr;
    float ur = sr[k], ui = si[k];
    sr[k] = ur + tr;        si[k] = ui + ti;
    sr[k + half] = ur - tr; si[k + half] = ui - ti;
    __syncthreads();
  }
}

__global__ __launch_bounds__(256) void k_fft_row_fwd(const float* __restrict__ x,
                                                     float2* __restrict__ xf) {
  __shared__ float sr[512], si[512], twr[256], twi[256];
  int t = threadIdx.x;
  int row = blockIdx.x & 511;
  int img = blockIdx.x >> 9;
  const float* p = x + (size_t)img * NPIX + (size_t)row * 512;
  init_tw(twr, twi, t);
  for (int i = t; i < 512; i += 256) { int r = brev9(i); sr[r] = p[i]; si[r] = 0.0f; }
  __syncthreads();
  fft512<true>(sr, si, twr, twi, t);
  float2* q = xf + (size_t)img * NPIX + (size_t)row * 512;
  for (int i = t; i < 512; i += 256) q[i] = make_float2(sr[i], si[i]);
}

__global__ __launch_bounds__(256) void k_fft_col_fwd(float2* __restrict__ xf) {
  __shared__ float sr[512], si[512], twr[256], twi[256];
  int t = threadIdx.x;
  int col = blockIdx.x & 511;
  int img = blockIdx.x >> 9;
  float2* p = xf + (size_t)img * NPIX + col;
  init_tw(twr, twi, t);
  for (int i = t; i < 512; i += 256) {
    int r = brev9(i);
    float2 v = p[(size_t)i * 512];
    sr[r] = v.x; si[r] = v.y;
  }
  __syncthreads();
  fft512<true>(sr, si, twr, twi, t);
  for (int i = t; i < 512; i += 256) p[(size_t)i * 512] = make_float2(sr[i], si[i]);
}

// x_mag with the all-axes fftshift quirk:
// xmag[b][c][h][w] = log10(|xf[(b+4)%8][(c+2)%3][(h+256)%512][(w+256)%512]| + 1)
__global__ __launch_bounds__(256) void k_xmag(const float2* __restrict__ xf,
                                              float* __restrict__ xmag) {
  int idx = blockIdx.x * 256 + threadIdx.x;   // 0 .. 6291455
  int w = idx & 511;
  int h = (idx >> 9) & 511;
  int bc = idx >> 18;            // 0..23
  int b = bc / 3, c = bc - 3 * b;
  int simg = ((b + 4) & 7) * 3 + ((c + 2) % 3);
  float2 v = xf[(size_t)simg * NPIX + (size_t)((h + 256) & 511) * 512 + ((w + 256) & 511)];
  xmag[idx] = log10f(sqrtf(v.x * v.x + v.y * v.y) + 1.0f);
}

// ---------------------------------------------------------------------------
// Conv stack, restructured for latency hiding: each thread owns a horizontal
// strip (2 pooled cols = 8 pre-pool positions, or 4 cols for conv3) x 8 output
// channels. Per ic-iteration: 18-24 independent global loads feed 288-576
// FMAs; weights are wave-uniform -> s_load (no VALU cost).
// ---------------------------------------------------------------------------

// conv1: 6->16, 512x512, pad1, relu, 2x2 avgpool -> out [b][16][256][256]
// grid (4, 32, 16): x covers 64 pooled cols, y covers 8 pooled rows, z = b*2+ocg
__global__ __launch_bounds__(256, 3) void k_conv1(const float* __restrict__ x,
                                                  const float* __restrict__ xmag,
                                                  const float* __restrict__ w1,
                                                  const float* __restrict__ b1,
                                                  float* __restrict__ out) {
  const int t = threadIdx.x;
  const int tx = t & 31, ty = t >> 5;
  const int pc0 = blockIdx.x * 64 + tx * 2;   // pooled col base (2 pooled cols)
  const int pr  = blockIdx.y * 8 + ty;        // pooled row
  const int z = blockIdx.z;
  const int b = z >> 1;
  const int og = (z & 1) * 8;                 // oc base (8 oc per thread)
  const int r0 = pr * 2 - 1;                  // input row base (4 rows)
  const int c0 = pc0 * 2 - 1;                 // input col base (6 cols)

  float acc[8][8];
  #pragma unroll
  for (int o = 0; o < 8; o++)
    #pragma unroll
    for (int q = 0; q < 8; q++) acc[o][q] = 0.0f;

  #pragma unroll 2
  for (int ic = 0; ic < 6; ic++) {
    const float* src = (ic < 3) ? (x + (size_t)(b * 3 + ic) * NPIX)
                                : (xmag + (size_t)(b * 3 + ic - 3) * NPIX);
    float patch[4][6];
    #pragma unroll
    for (int dy = 0; dy < 4; dy++) {
      int yy = r0 + dy;
      bool yok = (unsigned)yy < 512u;
      #pragma unroll
      for (int dx = 0; dx < 6; dx++) {
        int xx = c0 + dx;
        float v = 0.0f;
        if (yok && (unsigned)xx < 512u) v = src[yy * 512 + xx];
        patch[dy][dx] = v;
      }
    }
    #pragma unroll
    for (int o = 0; o < 8; o++) {
      const float* wk = w1 + (size_t)((og + o) * 6 + ic) * 9;
      float k0 = wk[0], k1 = wk[1], k2 = wk[2], k3 = wk[3], k4 = wk[4],
            k5 = wk[5], k6 = wk[6], k7 = wk[7], k8 = wk[8];
      #pragma unroll
      for (int py = 0; py < 2; py++)
        #pragma unroll
        for (int px = 0; px < 4; px++) {
          acc[o][py * 4 + px] +=
              k0 * patch[py][px]     + k1 * patch[py][px + 1]     + k2 * patch[py][px + 2]
            + k3 * patch[py + 1][px] + k4 * patch[py + 1][px + 1] + k5 * patch[py + 1][px + 2]
            + k6 * patch[py + 2][px] + k7 * patch[py + 2][px + 1] + k8 * patch[py + 2][px + 2];
        }
    }
  }
  #pragma unroll
  for (int o = 0; o < 8; o++) {
    float bias = b1[og + o];
    float p0 = fmaxf(acc[o][0] + bias, 0.0f) + fmaxf(acc[o][1] + bias, 0.0f)
             + fmaxf(acc[o][4] + bias, 0.0f) + fmaxf(acc[o][5] + bias, 0.0f);
    float p1 = fmaxf(acc[o][2] + bias, 0.0f) + fmaxf(acc[o][3] + bias, 0.0f)
             + fmaxf(acc[o][6] + bias, 0.0f) + fmaxf(acc[o][7] + bias, 0.0f);
    float2* q = (float2*)(out + ((size_t)(b * 16 + og + o) * 256 + pr) * 256 + pc0);
    *q = make_float2(p0 * 0.25f, p1 * 0.25f);
  }
}

// conv2: 16->32, 256x256, pad1, relu, pool -> out [b][32][128][128]
// grid (2, 16, 32): z = b*4 + ocg
__global__ __launch_bounds__(256, 3) void k_conv2(const float* __restrict__ in,
                                                  const float* __restrict__ w2,
                                                  const float* __restrict__ b2,
                                                  float* __restrict__ out) {
  const int t = threadIdx.x;
  const int tx = t & 31, ty = t >> 5;
  const int pc0 = blockIdx.x * 64 + tx * 2;
  const int pr  = blockIdx.y * 8 + ty;
  const int z = blockIdx.z;
  const int b = z >> 2;
  const int og = (z & 3) * 8;
  const int r0 = pr * 2 - 1;
  const int c0 = pc0 * 2 - 1;

  float acc[8][8];
  #pragma unroll
  for (int o = 0; o < 8; o++)
    #pragma unroll
    for (int q = 0; q < 8; q++) acc[o][q] = 0.0f;

  #pragma unroll 2
  for (int ic = 0; ic < 16; ic++) {
    const float* src = in + (size_t)(b * 16 + ic) * 65536;
    float patch[4][6];
    #pragma unroll
    for (int dy = 0; dy < 4; dy++) {
      int yy = r0 + dy;
      bool yok = (unsigned)yy < 256u;
      #pragma unroll
      for (int dx = 0; dx < 6; dx++) {
        int xx = c0 + dx;
        float v = 0.0f;
        if (yok && (unsigned)xx < 256u) v = src[yy * 256 + xx];
        patch[dy][dx] = v;
      }
    }
    #pragma unroll
    for (int o = 0; o < 8; o++) {
      const float* wk = w2 + (size_t)((og + o) * 16 + ic) * 9;
      float k0 = wk[0], k1 = wk[1], k2 = wk[2], k3 = wk[3], k4 = wk[4],
            k5 = wk[5], k6 = wk[6], k7 = wk[7], k8 = wk[8];
      #pragma unroll
      for (int py = 0; py < 2; py++)
        #pragma unroll
        for (int px = 0; px < 4; px++) {
          acc[o][py * 4 + px] +=
              k0 * patch[py][px]     + k1 * patch[py][px + 1]     + k2 * patch[py][px + 2]
            + k3 * patch[py + 1][px] + k4 * patch[py + 1][px + 1] + k5 * patch[py + 1][px + 2]
            + k6 * patch[py + 2][px] + k7 * patch[py + 2][px + 1] + k8 * patch[py + 2][px + 2];
        }
    }
  }
  #pragma unroll
  for (int o = 0; o < 8; o++) {
    float bias = b2[og + o];
    float p0 = fmaxf(acc[o][0] + bias, 0.0f) + fmaxf(acc[o][1] + bias, 0.0f)
             + fmaxf(acc[o][4] + bias, 0.0f) + fmaxf(acc[o][5] + bias, 0.0f);
    float p1 = fmaxf(acc[o][2] + bias, 0.0f) + fmaxf(acc[o][3] + bias, 0.0f)
             + fmaxf(acc[o][6] + bias, 0.0f) + fmaxf(acc[o][7] + bias, 0.0f);
    float2* q = (float2*)(out + ((size_t)(b * 32 + og + o) * 128 + pr) * 128 + pc0);
    *q = make_float2(p0 * 0.25f, p1 * 0.25f);
  }
}

// conv3: 32->64, 128x128, pad1, no relu, spatial mean (bias added in FC).
// grid (16, 64): x covers 8 rows, y = b*8 + ocg. Thread: 4 cols x 8 oc.
__global__ __launch_bounds__(256, 4) void k_conv3(const float* __restrict__ in,
                                                  const float* __restrict__ w3,
                                                  float* __restrict__ ymean) {
  const int t = threadIdx.x;
  const int tx = t & 31, ty = t >> 5;
  const int c0 = tx * 4 - 1;                  // 6 input cols
  const int r  = blockIdx.x * 8 + ty;         // output row
  const int z = blockIdx.y;
  const int b = z >> 3;
  const int og = (z & 7) * 8;

  float acc[8][4];
  #pragma unroll
  for (int o = 0; o < 8; o++)
    #pragma unroll
    for (int q = 0; q < 4; q++) acc[o][q] = 0.0f;

  #pragma unroll 2
  for (int ic = 0; ic < 32; ic++) {
    const float* src = in + (size_t)(b * 32 + ic) * 16384;
    float patch[3][6];
    #pragma unroll
    for (int dy = 0; dy < 3; dy++) {
      int yy = r - 1 + dy;
      bool yok = (unsigned)yy < 128u;
      #pragma unroll
      for (int dx = 0; dx < 6; dx++) {
        int xx = c0 + dx;
        float v = 0.0f;
        if (yok && (unsigned)xx < 128u) v = src[yy * 128 + xx];
        patch[dy][dx] = v;
      }
    }
    #pragma unroll
    for (int o = 0; o < 8; o++) {
      const float* wk = w3 + (size_t)((og + o) * 32 + ic) * 9;
      float k0 = wk[0], k1 = wk[1], k2 = wk[2], k3 = wk[3], k4 = wk[4],
            k5 = wk[5], k6 = wk[6], k7 = wk[7], k8 = wk[8];
      #pragma unroll
      for (int px = 0; px < 4; px++) {
        acc[o][px] += k0 * patch[0][px] + k1 * patch[0][px + 1] + k2 * patch[0][px + 2]
                    + k3 * patch[1][px] + k4 * patch[1][px + 1] + k5 * patch[1][px + 2]
                    + k6 * patch[2][px] + k7 * patch[2][px + 1] + k8 * patch[2][px + 2];
      }
    }
  }
  #pragma unroll
  for (int o = 0; o < 8; o++) {
    float v = (acc[o][0] + acc[o][1] + acc[o][2] + acc[o][3]) * (1.0f / 16384.0f);
    #pragma unroll
    for (int off = 32; off > 0; off >>= 1) v += __shfl_down(v, off, 64);
    if ((t & 63) == 0) atomicAdd(&ymean[b * 64 + og + o], v);
  }
}

// FC1 -> FC2 -> leaky_relu(0.01). Single block.
__global__ __launch_bounds__(256) void k_fc(const float* __restrict__ ymean,
                                            const float* __restrict__ b3,
                                            const float* __restrict__ fw1,
                                            const float* __restrict__ fb1,
                                            const float* __restrict__ fw2,
                                            const float* __restrict__ fb2,
                                            float* __restrict__ vs_out) {
  __shared__ float y[512];     // 8x64 (conv3 mean + bias)
  __shared__ float h1[2048];   // 8x256
  int t = threadIdx.x;
  for (int e = t; e < 512; e += 256) y[e] = ymean[e] + b3[e & 63];
  __syncthreads();
  for (int e = t; e < 2048; e += 256) {
    int b = e >> 8, j = e & 255;
    float s = fb1[j];
    for (int k = 0; k < 64; k++) s += y[b * 64 + k] * fw1[j * 64 + k];
    h1[e] = s;
  }
  __syncthreads();
  for (int e = t; e < 800; e += 256) {
    int b = e / 100, i = e - 100 * b;
    float s = fb2[i];
    for (int j = 0; j < 256; j++) s += h1[b * 256 + j] * fw2[i * 256 + j];
    vs_out[e] = (s >= 0.0f) ? s : 0.01f * s;
  }
}

// fq_mask[b][h][w] = value_set[b][searchsorted(radius_set, dist(h,w), 'left').clip(0,99)]
__global__ __launch_bounds__(256) void k_mask(const float* __restrict__ vs,
                                              float* __restrict__ fq_mask) {
  int idx = blockIdx.x * 256 + threadIdx.x;   // 0 .. 262143
  int h = idx >> 9, w = idx & 511;
  float da = (float)h - 256.0f, db = (float)w - 256.0f;
  float dist = sqrtf(da * da + db * db);      // exact integer radicand in f32
  // searchsorted left: first i with radius_set[i] >= dist; radius computed exactly as ref
  int lo = 0, hi = 100;
  while (lo < hi) {
    int mid = (lo + hi) >> 1;
    float r = (362.03867196751236f * (float)(mid + 1)) * 0.01f;
    if (r < dist) lo = mid + 1; else hi = mid;
  }
  int bin = lo > 99 ? 99 : lo;
  #pragma unroll
  for (int b = 0; b < 8; b++)
    fq_mask[(size_t)b * NPIX + idx] = vs[b * 100 + bin];
}

// inverse FFT over rows, with spectrum modulation fused on load.
// low[b][c][u][v] = xf[b][c][u][v] * fq_mask[(b+4)%8][(u+256)%512][(v+256)%512]
__global__ __launch_bounds__(256) void k_ifft_row_mod(float2* __restrict__ xf,
                                                      const float* __restrict__ fq_mask) {
  __shared__ float sr[512], si[512], twr[256], twi[256];
  int t = threadIdx.x;
  int row = blockIdx.x & 511;
  int img = blockIdx.x >> 9;
  int b = img / 3;
  int bm = (b + 4) & 7;
  const float* mrow = fq_mask + (size_t)bm * NPIX + (size_t)((row + 256) & 511) * 512;
  float2* p = xf + (size_t)img * NPIX + (size_t)row * 512;
  init_tw(twr, twi, t);
  for (int i = t; i < 512; i += 256) {
    int r = brev9(i);
    float m = mrow[(i + 256) & 511];
    float2 v = p[i];
    sr[r] = v.x * m; si[r] = v.y * m;
  }
  __syncthreads();
  fft512<false>(sr, si, twr, twi, t);
  for (int i = t; i < 512; i += 256) p[i] = make_float2(sr[i], si[i]);
}

// inverse FFT over columns, scale 1/(512*512), clip real -> lowpass output.
__global__ __launch_bounds__(256) void k_ifft_col_out(float2* __restrict__ xf,
                                                      float* __restrict__ lowpass) {
  __shared__ float sr[512], si[512], twr[256], twi[256];
  int t = threadIdx.x;
  int col = blockIdx.x & 511;
  int img = blockIdx.x >> 9;
  float2* p = xf + (size_t)img * NPIX + col;
  init_tw(twr, twi, t);
  for (int i = t; i < 512; i += 256) {
    int r = brev9(i);
    float2 v = p[(size_t)i * 512];
    sr[r] = v.x; si[r] = v.y;
  }
  __syncthreads();
  fft512<false>(sr, si, twr, twi, t);
  const float sc = 1.0f / 262144.0f;
  for (int i = t; i < 512; i += 256) {
    float v = sr[i] * sc;
    v = fminf(fmaxf(v, 0.0f), 1.0f);
    lowpass[(size_t)img * NPIX + (size_t)i * 512 + col] = v;
  }
}

extern "C" void kernel_launch(void* const* d_in, const int* in_sizes, int n_in,
                              void* d_out, int out_size, void* d_ws, size_t ws_size,
                              hipStream_t stream) {
  const float* x   = (const float*)d_in[0];
  const float* w1  = (const float*)d_in[1];
  const float* b1  = (const float*)d_in[2];
  const float* w2  = (const float*)d_in[3];
  const float* b2  = (const float*)d_in[4];
  const float* w3  = (const float*)d_in[5];
  const float* b3  = (const float*)d_in[6];
  const float* fw1 = (const float*)d_in[7];
  const float* fb1 = (const float*)d_in[8];
  const float* fw2 = (const float*)d_in[9];
  const float* fb2 = (const float*)d_in[10];

  float* lowpass = (float*)d_out;            // 8*3*512*512 = 6291456
  float* fq_mask = lowpass + 6291456;        // 8*512*512   = 2097152
  float* vs      = fq_mask + 2097152;        // 8*100       = 800

  // workspace layout (floats): xf complex 24*512*512 | xmag (aliased by pooled2) | pooled1 | ymean
  float* base    = (float*)d_ws;
  float2* xf     = (float2*)base;            // 12582912 floats
  float* xmag    = base + 12582912;          // 6291456 floats
  float* pooled1 = xmag + 6291456;           // 8388608 floats
  float* pooled2 = xmag;                     // alias: xmag dead after conv1 (needs 4194304)
  float* ymean   = pooled1 + 8388608;        // 512 floats

  // forward 2D FFT (rows then cols), unshifted layout
  k_fft_row_fwd<<<dim3(24 * 512), 256, 0, stream>>>(x, xf);
  k_fft_col_fwd<<<dim3(24 * 512), 256, 0, stream>>>(xf);

  // log-magnitude (with all-axes fftshift permutation)
  k_xmag<<<6291456 / 256, 256, 0, stream>>>(xf, xmag);

  // conv stack
  k_conv1<<<dim3(4, 32, 16), 256, 0, stream>>>(x, xmag, w1, b1, pooled1);
  k_conv2<<<dim3(2, 16, 32), 256, 0, stream>>>(pooled1, w2, b2, pooled2);
  hipMemsetAsync(ymean, 0, 512 * sizeof(float), stream);
  k_conv3<<<dim3(16, 64), 256, 0, stream>>>(pooled2, w3, ymean);

  // FC head -> value_set (written straight to d_out region)
  k_fc<<<1, 256, 0, stream>>>(ymean, b3, fw1, fb1, fw2, fb2, vs);

  // radial mask
  k_mask<<<1024, 256, 0, stream>>>(vs, fq_mask);

  // modulate + inverse 2D FFT + clip
  k_ifft_row_mod<<<dim3(24 * 512), 256, 0, stream>>>(xf, fq_mask);
  k_ifft_col_out<<<dim3(24 * 512), 256, 0, stream>>>(xf, lowpass);
}

// Round 3
// 662.861 us; speedup vs baseline: 1.5066x; 1.3756x over previous
//
#include <hip/hip_runtime.h>
#include <math.h>

#define NPIX 262144   // 512*512
#define FSTR 513      // LDS column stride for batch-8 FFT (pad 512+1)

__device__ __forceinline__ int brev9(int i) { return (int)(__brev((unsigned)i) >> 23); }

__device__ __forceinline__ void init_tw(float* twr, float* twi, int t) {
  // forward twiddles: exp(-i*pi*k/256), k=0..255
  if (t < 256) {
    float ang = -3.14159265358979323846f * (float)t / 256.0f;
    float s, c;
    sincosf(ang, &s, &c);
    twr[t] = c; twi[t] = s;
  }
}

// 8 x 512-pt radix-2 DIT FFTs in LDS, column-major: element p of FFT c at
// [c*FSTR + p]. 256 threads: c = t>>5 (8 FFTs), 32 threads x 8 butterflies
// per stage per FFT. Input must be stored bit-reversed by the caller.
template<bool FWD>
__device__ __forceinline__ void fft512x8(float* __restrict__ sr, float* __restrict__ si,
                                         const float* __restrict__ twr,
                                         const float* __restrict__ twi, int t) {
  const int c  = t >> 5;
  const int k0 = t & 31;
  float* cr = sr + c * FSTR;
  float* ci = si + c * FSTR;
  #pragma unroll
  for (int s = 0; s < 9; s++) {
    const int half = 1 << s;
    __syncthreads();
    #pragma unroll
    for (int m = 0; m < 8; m++) {
      int k  = k0 + 32 * m;
      int j  = k & (half - 1);
      int k2 = ((k >> s) << (s + 1)) | j;
      int tk = j << (8 - s);
      float wr = twr[tk];
      float wi = FWD ? twi[tk] : -twi[tk];
      float vr = cr[k2 + half], vi = ci[k2 + half];
      float tr = vr * wr - vi * wi;
      float ti = vr * wi + vi * wr;
      float ur = cr[k2], ui = ci[k2];
      cr[k2] = ur + tr;        ci[k2] = ui + ti;
      cr[k2 + half] = ur - tr; ci[k2 + half] = ui - ti;
    }
  }
  __syncthreads();
}

// forward FFT over 8 contiguous rows per block (real input).
__global__ __launch_bounds__(256) void k_fft_rows(const float* __restrict__ x,
                                                  float2* __restrict__ xf) {
  __shared__ float sr[8 * FSTR], si[8 * FSTR], twr[256], twi[256];
  int t = threadIdx.x;
  int img = blockIdx.x >> 6;
  int r0 = (blockIdx.x & 63) << 3;
  init_tw(twr, twi, t);
  const float4* p4 = (const float4*)(x + (size_t)img * NPIX + (size_t)r0 * 512);
  for (int e = t; e < 1024; e += 256) {       // 8 rows x 128 float4 (real)
    int row = e >> 7, w = e & 127;            // positions 4w..4w+3
    float4 f = p4[e];
    float* cr = sr + row * FSTR;
    float* ci = si + row * FSTR;
    int p = 4 * w;
    cr[brev9(p)]     = f.x;  ci[brev9(p)]     = 0.0f;
    cr[brev9(p + 1)] = f.y;  ci[brev9(p + 1)] = 0.0f;
    cr[brev9(p + 2)] = f.z;  ci[brev9(p + 2)] = 0.0f;
    cr[brev9(p + 3)] = f.w;  ci[brev9(p + 3)] = 0.0f;
  }
  fft512x8<true>(sr, si, twr, twi, t);
  float4* q4 = (float4*)(xf + (size_t)img * NPIX + (size_t)r0 * 512);
  for (int e = t; e < 2048; e += 256) {       // 8 rows x 256 float4 (complex)
    int row = e >> 8, u = e & 255;
    const float* cr = sr + row * FSTR;
    const float* ci = si + row * FSTR;
    q4[e] = make_float4(cr[2 * u], ci[2 * u], cr[2 * u + 1], ci[2 * u + 1]);
  }
}

// forward FFT over 8 adjacent columns per block (in-place on xf).
__global__ __launch_bounds__(256) void k_fft_cols(float2* __restrict__ xf) {
  __shared__ float sr[8 * FSTR], si[8 * FSTR], twr[256], twi[256];
  int t = threadIdx.x;
  int img = blockIdx.x >> 6;
  int c0 = (blockIdx.x & 63) << 3;
  init_tw(twr, twi, t);
  float2* base = xf + (size_t)img * NPIX + c0;
  // load mapping spreads bit-reversed LDS store banks: r = (e&31)<<4 | e>>7
  for (int e = t; e < 2048; e += 256) {
    int a = e & 31, q = (e >> 5) & 3, b = e >> 7;
    int r = (a << 4) | b;
    float4 f = *(const float4*)(base + (size_t)r * 512 + 2 * q);
    int rr = brev9(r);
    sr[(2 * q) * FSTR + rr]     = f.x;  si[(2 * q) * FSTR + rr]     = f.y;
    sr[(2 * q + 1) * FSTR + rr] = f.z;  si[(2 * q + 1) * FSTR + rr] = f.w;
  }
  fft512x8<true>(sr, si, twr, twi, t);
  for (int e = t; e < 2048; e += 256) {
    int r = e & 511, q = e >> 9;
    float4 f = make_float4(sr[(2 * q) * FSTR + r], si[(2 * q) * FSTR + r],
                           sr[(2 * q + 1) * FSTR + r], si[(2 * q + 1) * FSTR + r]);
    *(float4*)(base + (size_t)r * 512 + 2 * q) = f;
  }
}

// x_mag with the all-axes fftshift quirk:
// xmag[b][c][h][w] = log10(|xf[(b+4)%8][(c+2)%3][(h+256)%512][(w+256)%512]| + 1)
__global__ __launch_bounds__(256) void k_xmag(const float2* __restrict__ xf,
                                              float* __restrict__ xmag) {
  int idx = blockIdx.x * 256 + threadIdx.x;   // 0 .. 6291455
  int w = idx & 511;
  int h = (idx >> 9) & 511;
  int bc = idx >> 18;            // 0..23
  int b = bc / 3, c = bc - 3 * b;
  int simg = ((b + 4) & 7) * 3 + ((c + 2) % 3);
  float2 v = xf[(size_t)simg * NPIX + (size_t)((h + 256) & 511) * 512 + ((w + 256) & 511)];
  xmag[idx] = log10f(sqrtf(v.x * v.x + v.y * v.y) + 1.0f);
}

// ---------------------------------------------------------------------------
// LDS-staged conv stack. Per ic: block stages an input window with coalesced
// dword loads; threads read 16B-aligned patches from LDS (col c of the window
// at LDS index c+1 relative shift -> patch base 4*tx is float4-aligned).
// ---------------------------------------------------------------------------

// conv1: 6->16, 512x512, pad1, relu, 2x2 avgpool -> [b][16][256][256]
// grid (4, 32, 16); block 256 = 32 tx (2 pooled cols each) x 8 ty (1 pooled row)
__global__ __launch_bounds__(256) void k_conv1(const float* __restrict__ x,
                                               const float* __restrict__ xmag,
                                               const float* __restrict__ w1,
                                               const float* __restrict__ b1,
                                               float* __restrict__ out) {
  __shared__ float tile[18 * 132];
  const int t = threadIdx.x;
  const int tx = t & 31, ty = t >> 5;
  const int PC0 = blockIdx.x * 64;
  const int PR0 = blockIdx.y * 8;
  const int b  = blockIdx.z >> 1;
  const int og = (blockIdx.z & 1) * 8;
  const int R0 = PR0 * 2 - 1;    // input row of tile row 0
  const int C0 = PC0 * 2 - 1;    // input col of tile col 0

  float acc[8][8];
  #pragma unroll
  for (int o = 0; o < 8; o++)
    #pragma unroll
    for (int q = 0; q < 8; q++) acc[o][q] = 0.0f;

  for (int ic = 0; ic < 6; ic++) {
    const float* src = (ic < 3) ? (x + (size_t)(b * 3 + ic) * NPIX)
                                : (xmag + (size_t)(b * 3 + ic - 3) * NPIX);
    __syncthreads();
    for (int e = t; e < 18 * 130; e += 256) {
      int i = e / 130, j = e - i * 130;
      int rr = R0 + i, cc = C0 + j;
      float v = 0.0f;
      if ((unsigned)rr < 512u && (unsigned)cc < 512u) v = src[rr * 512 + cc];
      tile[i * 132 + j] = v;
    }
    __syncthreads();
    float patch[4][6];
    #pragma unroll
    for (int dy = 0; dy < 4; dy++) {
      const float* rp = tile + (2 * ty + dy) * 132 + 4 * tx;
      float4 f = *(const float4*)rp;
      float2 g = *(const float2*)(rp + 4);
      patch[dy][0] = f.x; patch[dy][1] = f.y; patch[dy][2] = f.z;
      patch[dy][3] = f.w; patch[dy][4] = g.x; patch[dy][5] = g.y;
    }
    #pragma unroll
    for (int o = 0; o < 8; o++) {
      const float* wk = w1 + (size_t)((og + o) * 6 + ic) * 9;
      float k0 = wk[0], k1 = wk[1], k2 = wk[2], k3 = wk[3], k4 = wk[4],
            k5 = wk[5], k6 = wk[6], k7 = wk[7], k8 = wk[8];
      #pragma unroll
      for (int py = 0; py < 2; py++)
        #pragma unroll
        for (int px = 0; px < 4; px++) {
          acc[o][py * 4 + px] +=
              k0 * patch[py][px]     + k1 * patch[py][px + 1]     + k2 * patch[py][px + 2]
            + k3 * patch[py + 1][px] + k4 * patch[py + 1][px + 1] + k5 * patch[py + 1][px + 2]
            + k6 * patch[py + 2][px] + k7 * patch[py + 2][px + 1] + k8 * patch[py + 2][px + 2];
        }
    }
  }
  #pragma unroll
  for (int o = 0; o < 8; o++) {
    float bias = b1[og + o];
    float p0 = fmaxf(acc[o][0] + bias, 0.0f) + fmaxf(acc[o][1] + bias, 0.0f)
             + fmaxf(acc[o][4] + bias, 0.0f) + fmaxf(acc[o][5] + bias, 0.0f);
    float p1 = fmaxf(acc[o][2] + bias, 0.0f) + fmaxf(acc[o][3] + bias, 0.0f)
             + fmaxf(acc[o][6] + bias, 0.0f) + fmaxf(acc[o][7] + bias, 0.0f);
    float2* q = (float2*)(out + ((size_t)(b * 16 + og + o) * 256 + PR0 + ty) * 256 + PC0 + 2 * tx);
    *q = make_float2(p0 * 0.25f, p1 * 0.25f);
  }
}

// conv2: 16->32, 256x256, pad1, relu, pool -> [b][32][128][128]
// grid (2, 16, 32)
__global__ __launch_bounds__(256) void k_conv2(const float* __restrict__ in,
                                               const float* __restrict__ w2,
                                               const float* __restrict__ b2,
                                               float* __restrict__ out) {
  __shared__ float tile[18 * 132];
  const int t = threadIdx.x;
  const int tx = t & 31, ty = t >> 5;
  const int PC0 = blockIdx.x * 64;
  const int PR0 = blockIdx.y * 8;
  const int b  = blockIdx.z >> 2;
  const int og = (blockIdx.z & 3) * 8;
  const int R0 = PR0 * 2 - 1;
  const int C0 = PC0 * 2 - 1;

  float acc[8][8];
  #pragma unroll
  for (int o = 0; o < 8; o++)
    #pragma unroll
    for (int q = 0; q < 8; q++) acc[o][q] = 0.0f;

  for (int ic = 0; ic < 16; ic++) {
    const float* src = in + (size_t)(b * 16 + ic) * 65536;
    __syncthreads();
    for (int e = t; e < 18 * 130; e += 256) {
      int i = e / 130, j = e - i * 130;
      int rr = R0 + i, cc = C0 + j;
      float v = 0.0f;
      if ((unsigned)rr < 256u && (unsigned)cc < 256u) v = src[rr * 256 + cc];
      tile[i * 132 + j] = v;
    }
    __syncthreads();
    float patch[4][6];
    #pragma unroll
    for (int dy = 0; dy < 4; dy++) {
      const float* rp = tile + (2 * ty + dy) * 132 + 4 * tx;
      float4 f = *(const float4*)rp;
      float2 g = *(const float2*)(rp + 4);
      patch[dy][0] = f.x; patch[dy][1] = f.y; patch[dy][2] = f.z;
      patch[dy][3] = f.w; patch[dy][4] = g.x; patch[dy][5] = g.y;
    }
    #pragma unroll
    for (int o = 0; o < 8; o++) {
      const float* wk = w2 + (size_t)((og + o) * 16 + ic) * 9;
      float k0 = wk[0], k1 = wk[1], k2 = wk[2], k3 = wk[3], k4 = wk[4],
            k5 = wk[5], k6 = wk[6], k7 = wk[7], k8 = wk[8];
      #pragma unroll
      for (int py = 0; py < 2; py++)
        #pragma unroll
        for (int px = 0; px < 4; px++) {
          acc[o][py * 4 + px] +=
              k0 * patch[py][px]     + k1 * patch[py][px + 1]     + k2 * patch[py][px + 2]
            + k3 * patch[py + 1][px] + k4 * patch[py + 1][px + 1] + k5 * patch[py + 1][px + 2]
            + k6 * patch[py + 2][px] + k7 * patch[py + 2][px + 1] + k8 * patch[py + 2][px + 2];
        }
    }
  }
  #pragma unroll
  for (int o = 0; o < 8; o++) {
    float bias = b2[og + o];
    float p0 = fmaxf(acc[o][0] + bias, 0.0f) + fmaxf(acc[o][1] + bias, 0.0f)
             + fmaxf(acc[o][4] + bias, 0.0f) + fmaxf(acc[o][5] + bias, 0.0f);
    float p1 = fmaxf(acc[o][2] + bias, 0.0f) + fmaxf(acc[o][3] + bias, 0.0f)
             + fmaxf(acc[o][6] + bias, 0.0f) + fmaxf(acc[o][7] + bias, 0.0f);
    float2* q = (float2*)(out + ((size_t)(b * 32 + og + o) * 128 + PR0 + ty) * 128 + PC0 + 2 * tx);
    *q = make_float2(p0 * 0.25f, p1 * 0.25f);
  }
}

// conv3: 32->64, 128x128, pad1, spatial mean (bias added in FC).
// grid (1, 16, 64); block 256 = 32 tx (4 cols each) x 8 ty (1 row)
__global__ __launch_bounds__(256) void k_conv3(const float* __restrict__ in,
                                               const float* __restrict__ w3,
                                               float* __restrict__ ymean) {
  __shared__ float tile[10 * 132];
  const int t = threadIdx.x;
  const int tx = t & 31, ty = t >> 5;
  const int R0 = blockIdx.y * 8;              // output row base
  const int b  = blockIdx.z >> 3;
  const int og = (blockIdx.z & 7) * 8;

  float acc[8][4];
  #pragma unroll
  for (int o = 0; o < 8; o++)
    #pragma unroll
    for (int q = 0; q < 4; q++) acc[o][q] = 0.0f;

  for (int ic = 0; ic < 32; ic++) {
    const float* src = in + (size_t)(b * 32 + ic) * 16384;
    __syncthreads();
    for (int e = t; e < 10 * 130; e += 256) {
      int i = e / 130, j = e - i * 130;
      int rr = R0 - 1 + i, cc = j - 1;
      float v = 0.0f;
      if ((unsigned)rr < 128u && (unsigned)cc < 128u) v = src[rr * 128 + cc];
      tile[i * 132 + j] = v;
    }
    __syncthreads();
    float patch[3][6];
    #pragma unroll
    for (int dy = 0; dy < 3; dy++) {
      const float* rp = tile + (ty + dy) * 132 + 4 * tx;
      float4 f = *(const float4*)rp;
      float2 g = *(const float2*)(rp + 4);
      patch[dy][0] = f.x; patch[dy][1] = f.y; patch[dy][2] = f.z;
      patch[dy][3] = f.w; patch[dy][4] = g.x; patch[dy][5] = g.y;
    }
    #pragma unroll
    for (int o = 0; o < 8; o++) {
      const float* wk = w3 + (size_t)((og + o) * 32 + ic) * 9;
      float k0 = wk[0], k1 = wk[1], k2 = wk[2], k3 = wk[3], k4 = wk[4],
            k5 = wk[5], k6 = wk[6], k7 = wk[7], k8 = wk[8];
      #pragma unroll
      for (int px = 0; px < 4; px++) {
        acc[o][px] += k0 * patch[0][px] + k1 * patch[0][px + 1] + k2 * patch[0][px + 2]
                    + k3 * patch[1][px] + k4 * patch[1][px + 1] + k5 * patch[1][px + 2]
                    + k6 * patch[2][px] + k7 * patch[2][px + 1] + k8 * patch[2][px + 2];
      }
    }
  }
  #pragma unroll
  for (int o = 0; o < 8; o++) {
    float v = (acc[o][0] + acc[o][1] + acc[o][2] + acc[o][3]) * (1.0f / 16384.0f);
    #pragma unroll
    for (int off = 32; off > 0; off >>= 1) v += __shfl_down(v, off, 64);
    if ((t & 63) == 0) atomicAdd(&ymean[b * 64 + og + o], v);
  }
}

// FC1 -> FC2 -> leaky_relu(0.01). Single block.
__global__ __launch_bounds__(256) void k_fc(const float* __restrict__ ymean,
                                            const float* __restrict__ b3,
                                            const float* __restrict__ fw1,
                                            const float* __restrict__ fb1,
                                            const float* __restrict__ fw2,
                                            const float* __restrict__ fb2,
                                            float* __restrict__ vs_out) {
  __shared__ float y[512];     // 8x64
  __shared__ float h1[2048];   // 8x256
  int t = threadIdx.x;
  for (int e = t; e < 512; e += 256) y[e] = ymean[e] + b3[e & 63];
  __syncthreads();
  for (int e = t; e < 2048; e += 256) {
    int b = e >> 8, j = e & 255;
    float s = fb1[j];
    for (int k = 0; k < 64; k++) s += y[b * 64 + k] * fw1[j * 64 + k];
    h1[e] = s;
  }
  __syncthreads();
  for (int e = t; e < 800; e += 256) {
    int b = e / 100, i = e - 100 * b;
    float s = fb2[i];
    for (int j = 0; j < 256; j++) s += h1[b * 256 + j] * fw2[i * 256 + j];
    vs_out[e] = (s >= 0.0f) ? s : 0.01f * s;
  }
}

// fq_mask[b][h][w] = value_set[b][searchsorted(radius_set, dist(h,w), 'left').clip(0,99)]
__global__ __launch_bounds__(256) void k_mask(const float* __restrict__ vs,
                                              float* __restrict__ fq_mask) {
  int idx = blockIdx.x * 256 + threadIdx.x;
  int h = idx >> 9, w = idx & 511;
  float da = (float)h - 256.0f, db = (float)w - 256.0f;
  float dist = sqrtf(da * da + db * db);
  int lo = 0, hi = 100;
  while (lo < hi) {
    int mid = (lo + hi) >> 1;
    float r = (362.03867196751236f * (float)(mid + 1)) * 0.01f;
    if (r < dist) lo = mid + 1; else hi = mid;
  }
  int bin = lo > 99 ? 99 : lo;
  #pragma unroll
  for (int b = 0; b < 8; b++)
    fq_mask[(size_t)b * NPIX + idx] = vs[b * 100 + bin];
}

// inverse FFT over 8 rows per block, spectrum modulation fused on load.
// low[b][c][u][v] = xf[b][c][u][v] * fq_mask[(b+4)%8][(u+256)%512][(v+256)%512]
__global__ __launch_bounds__(256) void k_ifft_rows_mod(float2* __restrict__ xf,
                                                       const float* __restrict__ fq_mask) {
  __shared__ float sr[8 * FSTR], si[8 * FSTR], twr[256], twi[256];
  int t = threadIdx.x;
  int img = blockIdx.x >> 6;
  int r0 = (blockIdx.x & 63) << 3;
  int bm = ((img / 3) + 4) & 7;
  init_tw(twr, twi, t);
  const float* mbase = fq_mask + (size_t)bm * NPIX;
  float4* base4 = (float4*)(xf + (size_t)img * NPIX + (size_t)r0 * 512);
  // mapping: u[1:0]=e[1:0], u[6:3]=e[5:2], u[2]=e[6], u[7]=e[7], row=e>>8
  for (int e = t; e < 2048; e += 256) {
    int u = (e & 3) | (((e >> 2) & 15) << 3) | (((e >> 6) & 1) << 2) | (((e >> 7) & 1) << 7);
    int row = e >> 8;
    float4 f = base4[row * 256 + u];
    int p0 = 2 * u;
    const float* mrow = mbase + (size_t)((r0 + row + 256) & 511) * 512;
    float2 m = *(const float2*)(mrow + ((p0 + 256) & 511));
    int rr0 = brev9(p0);
    float* cr = sr + row * FSTR;
    float* ci = si + row * FSTR;
    cr[rr0]       = f.x * m.x;  ci[rr0]       = f.y * m.x;
    cr[rr0 + 256] = f.z * m.y;  ci[rr0 + 256] = f.w * m.y;  // brev9(p0+1)=rr0+256
  }
  fft512x8<false>(sr, si, twr, twi, t);
  for (int e = t; e < 2048; e += 256) {
    int row = e >> 8, u = e & 255;
    const float* cr = sr + row * FSTR;
    const float* ci = si + row * FSTR;
    base4[e] = make_float4(cr[2 * u], ci[2 * u], cr[2 * u + 1], ci[2 * u + 1]);
  }
}

// inverse FFT over 8 columns per block, scale 1/N, clip -> lowpass.
__global__ __launch_bounds__(256) void k_ifft_cols_out(const float2* __restrict__ xf,
                                                       float* __restrict__ lowpass) {
  __shared__ float sr[8 * FSTR], si[8 * FSTR], twr[256], twi[256];
  int t = threadIdx.x;
  int img = blockIdx.x >> 6;
  int c0 = (blockIdx.x & 63) << 3;
  init_tw(twr, twi, t);
  const float2* base = xf + (size_t)img * NPIX + c0;
  for (int e = t; e < 2048; e += 256) {
    int a = e & 31, q = (e >> 5) & 3, b = e >> 7;
    int r = (a << 4) | b;
    float4 f = *(const float4*)(base + (size_t)r * 512 + 2 * q);
    int rr = brev9(r);
    sr[(2 * q) * FSTR + rr]     = f.x;  si[(2 * q) * FSTR + rr]     = f.y;
    sr[(2 * q + 1) * FSTR + rr] = f.z;  si[(2 * q + 1) * FSTR + rr] = f.w;
  }
  fft512x8<false>(sr, si, twr, twi, t);
  const float sc = 1.0f / 262144.0f;
  float* obase = lowpass + (size_t)img * NPIX + c0;
  for (int e = t; e < 2048; e += 256) {
    int r = e & 511, q = e >> 9;
    float v0 = fminf(fmaxf(sr[(2 * q) * FSTR + r] * sc, 0.0f), 1.0f);
    float v1 = fminf(fmaxf(sr[(2 * q + 1) * FSTR + r] * sc, 0.0f), 1.0f);
    *(float2*)(obase + (size_t)r * 512 + 2 * q) = make_float2(v0, v1);
  }
}

extern "C" void kernel_launch(void* const* d_in, const int* in_sizes, int n_in,
                              void* d_out, int out_size, void* d_ws, size_t ws_size,
                              hipStream_t stream) {
  const float* x   = (const float*)d_in[0];
  const float* w1  = (const float*)d_in[1];
  const float* b1  = (const float*)d_in[2];
  const float* w2  = (const float*)d_in[3];
  const float* b2  = (const float*)d_in[4];
  const float* w3  = (const float*)d_in[5];
  const float* b3  = (const float*)d_in[6];
  const float* fw1 = (const float*)d_in[7];
  const float* fb1 = (const float*)d_in[8];
  const float* fw2 = (const float*)d_in[9];
  const float* fb2 = (const float*)d_in[10];

  float* lowpass = (float*)d_out;            // 8*3*512*512
  float* fq_mask = lowpass + 6291456;        // 8*512*512
  float* vs      = fq_mask + 2097152;        // 8*100

  float* base    = (float*)d_ws;
  float2* xf     = (float2*)base;            // 12582912 floats
  float* xmag    = base + 12582912;          // 6291456 floats
  float* pooled1 = xmag + 6291456;           // 8388608 floats
  float* pooled2 = xmag;                     // alias: xmag dead after conv1
  float* ymean   = pooled1 + 8388608;        // 512 floats

  k_fft_rows<<<dim3(24 * 64), 256, 0, stream>>>(x, xf);
  k_fft_cols<<<dim3(24 * 64), 256, 0, stream>>>(xf);

  k_xmag<<<6291456 / 256, 256, 0, stream>>>(xf, xmag);

  k_conv1<<<dim3(4, 32, 16), 256, 0, stream>>>(x, xmag, w1, b1, pooled1);
  k_conv2<<<dim3(2, 16, 32), 256, 0, stream>>>(pooled1, w2, b2, pooled2);
  hipMemsetAsync(ymean, 0, 512 * sizeof(float), stream);
  k_conv3<<<dim3(1, 16, 64), 256, 0, stream>>>(pooled2, w3, ymean);

  k_fc<<<1, 256, 0, stream>>>(ymean, b3, fw1, fb1, fw2, fb2, vs);
  k_mask<<<1024, 256, 0, stream>>>(vs, fq_mask);

  k_ifft_rows_mod<<<dim3(24 * 64), 256, 0, stream>>>(xf, fq_mask);
  k_ifft_cols_out<<<dim3(24 * 64), 256, 0, stream>>>(xf, lowpass);
}